// Round 6
// baseline (109.217 us; speedup 1.0000x reference)
//
#include <hip/hip_runtime.h>
#include <math.h>
#include <stdint.h>

#define RB 256      // block size
#define KB 256      // rank blocks (n / IK)
#define IK 32       // i-keys owned per rank block
#define JS 32       // j-iterations per thread in rank phase (n / RB)
#define G  32       // gt source groups (partial buffers)
#define GTB (G * 4) // gt blocks: G groups x 4 m-chunks
#define GCH 256     // sources per gt group (n / G)
#define GM 1024     // Gauss-transform grid points

#define SCALE 0.84932180028801904f   // 1/sqrt(2 ln2): exp(-d^2/2) = exp2(-(SCALE*d)^2)
#define SQRT2PI 2.5066282746310002f
#define KFP 0.46971863934f           // 1/(SCALE*sqrt(2pi)) : dPhiSum/dx = KFP*A
#define LN2 0.69314718056f

__device__ __forceinline__ uint64_t order_key(float f, int idx) {
  unsigned u = __float_as_uint(f);
  u = (u & 0x80000000u) ? ~u : (u | 0x80000000u);
  return ((uint64_t)u << 32) | (unsigned)idx;
}

__device__ __forceinline__ float e_of(const float* theta, const float* dur, int i) {
  return logf(dur[i] + 1e-32f) - theta[i];   // deterministic: identical everywhere
}

// grid geometry from the sorted endpoints (identical fp ops in every consumer)
__device__ __forceinline__ void grid_geom(const float2* xe, int n, float* x0, float* hx) {
  float a = xe[0].x - 7.0f;        // ~8 sigma margin in prescaled units
  float b = xe[n - 1].x + 7.0f;
  *x0 = a;
  *hx = (b - a) / (float)(GM - 1);
}

// ---------------------------------------------------------------------------
// Kernel 1: full rank + scatter in ONE dispatch. Block b owns i-keys
// [32b, 32b+32) in registers; each thread streams a 32-element j-stripe and
// compares against all 32 keys. shfl + LDS reduce -> complete ranks -> scatter.
// Side duty: block 16 zeroes the done-counter (partials need no zero-init).
// ---------------------------------------------------------------------------
__global__ __launch_bounds__(RB) void rank_scatter_kernel(
    const float* __restrict__ theta, const float* __restrict__ dur,
    const int* __restrict__ ev, float2* __restrict__ xe,
    float* __restrict__ th_s, unsigned* __restrict__ done, int n) {
  __shared__ uint64_t kt[IK];
  __shared__ int part[4 * IK];
  const int tid = threadIdx.x, bid = blockIdx.x;
  const int k0 = bid * IK;

  if (tid < IK) kt[tid] = order_key(e_of(theta, dur, k0 + tid), k0 + tid);
  if (bid == 16 && tid == 0) *done = 0u;
  __syncthreads();

  uint64_t ki[IK];
  int cnt[IK];
  #pragma unroll
  for (int p = 0; p < IK; ++p) { ki[p] = kt[p]; cnt[p] = 0; }

  #pragma unroll 4
  for (int s = 0; s < JS; ++s) {
    int j = s * RB + tid;                            // coalesced stripe
    uint64_t jk = order_key(e_of(theta, dur, j), j);
    #pragma unroll
    for (int p = 0; p < IK; ++p) cnt[p] += (jk < ki[p]) ? 1 : 0;
  }

  // reduce each of the 32 counts across the 64-lane wave, then across waves
  #pragma unroll
  for (int p = 0; p < IK; ++p) {
    #pragma unroll
    for (int off = 32; off > 0; off >>= 1) cnt[p] += __shfl_down(cnt[p], off, 64);
  }
  int wave = tid >> 6, lane = tid & 63;
  if (lane == 0) {
    #pragma unroll
    for (int p = 0; p < IK; ++p) part[wave * IK + p] = cnt[p];
  }
  __syncthreads();

  if (tid < IK) {
    int r = part[tid] + part[IK + tid] + part[2 * IK + tid] + part[3 * IK + tid];
    int k = k0 + tid;
    ((float*)&xe[r])[0] = SCALE * e_of(theta, dur, k);   // scatter (distinct dword)
    ((float*)&xe[k])[1] = (float)ev[r];                  // inverse-perm side reorder
    th_s[k] = theta[r];
  }
}

// ---------------------------------------------------------------------------
// Kernel 2: Gauss transform -> per-group PARTIALS (plain stores; the round-5
// atomicAdd tree serialized 2048 RMWs/line at the coherent point = ~37 us).
// Block (g, c): sources [g*256,(g+1)*256) staged in LDS, grid points
// m = c*256+tid. Stores part[g*4096 + seg*1024 + m], seg = A|B|F|D.
// Last-block (ticket) tail: reduce 32 partials -> LDS gsum (float4, unrolled
// for in-flight depth), then Hermite interpolation + loss, direct out store.
// ---------------------------------------------------------------------------
__global__ __launch_bounds__(RB) void gt_final_kernel(
    const float2* __restrict__ xe, const float* __restrict__ th_s,
    float* __restrict__ part, unsigned* __restrict__ done,
    float* __restrict__ out, int n) {
  __shared__ float2 cst[GCH];
  __shared__ float gsum[4 * GM];          // 16 KB, tail only
  __shared__ float red[RB / 64];
  __shared__ unsigned tick;
  const int tid = threadIdx.x, bid = blockIdx.x;

  float x0, hx;
  grid_geom(xe, n, &x0, &hx);

  // ---- gt phase ----
  {
    const int c = bid & 3, g = bid >> 2;
    int m = c * RB + tid;
    float xm = fmaf((float)m, hx, x0);
    cst[tid] = xe[g * GCH + tid];          // stage 256 sources
    __syncthreads();
    const float P2S = 0.39169197f;  // 0.47047*sqrt(ln2): t = 1/(1+p|d|/sqrt2)
    float a = 0.0f, b = 0.0f, f = 0.0f, d = 0.0f;
    #pragma unroll 8
    for (int jj = 0; jj < GCH; ++jj) {
      float2 q = cst[jj];                  // LDS broadcast
      float dp = xm - q.x;
      float g2 = __builtin_amdgcn_exp2f(-(dp * dp));  // exp(-d^2/2)
      float evg = q.y * g2;
      a += g2;
      b += evg;
      d = fmaf(dp, evg, d);
      // A&S 7.1.25 erf (p=0.47047, |err|<=2.5e-5), reuses g2
      float tt = __builtin_amdgcn_rcpf(fmaf(P2S, __builtin_fabsf(dp), 1.0f));
      float poly = tt * (0.3480242f + tt * (-0.0958798f + tt * 0.7478556f));
      f += __builtin_copysignf(fmaf(-poly, g2, 1.0f), dp);   // sign*erf
    }
    float* pg = part + g * (4 * GM);
    pg[m]          = a;                    // plain coalesced stores, no contention
    pg[GM + m]     = b;
    pg[2 * GM + m] = 0.5f * (float)GCH + 0.5f * f;   // Phi = .5 + .5*sum(erf)
    pg[3 * GM + m] = d;
  }

  // ---- last-block handoff ----
  __syncthreads();                         // drains this block's stores (vmcnt)
  if (tid == 0) {
    __threadfence();                       // release: wb L2 -> device-visible
    tick = __hip_atomic_fetch_add(done, 1u, __ATOMIC_ACQ_REL,
                                  __HIP_MEMORY_SCOPE_AGENT);
  }
  __syncthreads();
  if (tick != GTB - 1) return;             // all but one block exit (no spinning)

  // ---- tail: reduce partials into LDS ----
  __threadfence();                         // acquire: invalidate stale lines
  {
    const float4* p4 = (const float4*)part;
    float4 a0 = {0, 0, 0, 0}, a1 = {0, 0, 0, 0}, a2 = {0, 0, 0, 0}, a3 = {0, 0, 0, 0};
    #pragma unroll 8
    for (int g = 0; g < G; ++g) {          // 128 float4 loads/thread, deep in-flight
      const float4* pg = p4 + g * GM;      // 4*GM floats = GM float4s per group
      float4 v0 = pg[tid];
      float4 v1 = pg[256 + tid];
      float4 v2 = pg[512 + tid];
      float4 v3 = pg[768 + tid];
      a0.x += v0.x; a0.y += v0.y; a0.z += v0.z; a0.w += v0.w;
      a1.x += v1.x; a1.y += v1.y; a1.z += v1.z; a1.w += v1.w;
      a2.x += v2.x; a2.y += v2.y; a2.z += v2.z; a2.w += v2.w;
      a3.x += v3.x; a3.y += v3.y; a3.z += v3.z; a3.w += v3.w;
    }
    ((float4*)gsum)[tid]       = a0;
    ((float4*)gsum)[256 + tid] = a1;
    ((float4*)gsum)[512 + tid] = a2;
    ((float4*)gsum)[768 + tid] = a3;
  }
  __syncthreads();

  // ---- tail: Hermite interpolation + loss (gsum in LDS) ----
  const float* A = gsum;
  const float* B = gsum + GM;
  const float* F = gsum + 2 * GM;
  const float* D = gsum + 3 * GM;

  float acc = 0.0f;
  for (int i = tid; i < n; i += RB) {
    float2 q = xe[i];
    float u = (q.x - x0) * __builtin_amdgcn_rcpf(hx);
    int m = (int)u;
    m = min(max(m, 0), GM - 2);
    float t = u - (float)m;
    t = fminf(fmaxf(t, 0.0f), 1.0f);
    float t2 = t * t, t3 = t2 * t;
    float h00 = 2.0f * t3 - 3.0f * t2 + 1.0f;
    float h01 = 3.0f * t2 - 2.0f * t3;
    float h10 = t3 - 2.0f * t2 + t;
    float h11 = t3 - t2;
    float Fi = F[m] * h00 + F[m + 1] * h01 +
               hx * KFP * (A[m] * h10 + A[m + 1] * h11);
    float Bi = B[m] * h00 + B[m + 1] * h01 -
               2.0f * LN2 * hx * (D[m] * h10 + D[m + 1] * h11);
    const float fn = (float)n;
    float condE = fmaxf(Bi, 0.0f) * (1.0f / SQRT2PI) / fn + fn * 1e-32f;
    float surv = fmaxf(Fi, 0.25f) / fn;    // exact math gives Fi >= 0.5
    acc += (__logf(condE) - __logf(surv) + th_s[i]) * q.y;
  }

  #pragma unroll
  for (int off = 32; off > 0; off >>= 1) acc += __shfl_down(acc, off, 64);
  int wave = tid >> 6, lane = tid & 63;
  if (lane == 0) red[wave] = acc;
  __syncthreads();
  if (tid == 0) {
    float s = 0.0f;
    #pragma unroll
    for (int w = 0; w < RB / 64; ++w) s += red[w];
    out[0] = -s / (float)n;                // single writer: direct store
  }
}

extern "C" void kernel_launch(void* const* d_in, const int* in_sizes, int n_in,
                              void* d_out, int out_size, void* d_ws, size_t ws_size,
                              hipStream_t stream) {
  const float* theta = (const float*)d_in[0];   // log_h (n,1) fp32
  const float* dur   = (const float*)d_in[1];   // durations (n,) fp32
  const int*   ev    = (const int*)d_in[2];     // events (n,) int32
  float* out = (float*)d_out;
  int n = in_sizes[1];

  // workspace layout (16-byte aligned first for float4 access)
  char* ws = (char*)d_ws;
  float*    part = (float*)ws;     ws += G * 4 * GM * sizeof(float);  // partials
  float2*   xe   = (float2*)ws;    ws += n * sizeof(float2);
  float*    th_s = (float*)ws;     ws += n * sizeof(float);
  unsigned* done = (unsigned*)ws;  ws += sizeof(unsigned);

  rank_scatter_kernel<<<KB, RB, 0, stream>>>(theta, dur, ev, xe, th_s, done, n);
  gt_final_kernel<<<GTB, RB, 0, stream>>>(xe, th_s, part, done, out, n);
}

// Round 7
// 89.807 us; speedup vs baseline: 1.2161x; 1.2161x over previous
//
#include <hip/hip_runtime.h>
#include <math.h>
#include <stdint.h>

#define RB 256      // block size
#define KB 256      // rank blocks (n / IK)
#define IK 32       // i-keys owned per rank block
#define JS 32       // j-iterations per thread in rank phase (n / RB)
#define G  64       // gt source groups (partial buffers)
#define GTB (G * 4) // gt blocks: G groups x 4 m-chunks
#define GCH 128     // sources per gt group (n / G)
#define GM 1024     // Gauss-transform grid points
#define FB 32       // final blocks (n / RB)

#define SCALE 0.84932180028801904f   // 1/sqrt(2 ln2): exp(-d^2/2) = exp2(-(SCALE*d)^2)
#define SQRT2PI 2.5066282746310002f
#define KFP 0.46971863934f           // 1/(SCALE*sqrt(2pi)) : dPhiSum/dx = KFP*A
#define LN2 0.69314718056f

__device__ __forceinline__ uint64_t order_key(float f, int idx) {
  unsigned u = __float_as_uint(f);
  u = (u & 0x80000000u) ? ~u : (u | 0x80000000u);
  return ((uint64_t)u << 32) | (unsigned)idx;
}

__device__ __forceinline__ float e_of(const float* theta, const float* dur, int i) {
  return logf(dur[i] + 1e-32f) - theta[i];   // deterministic: identical everywhere
}

// grid geometry from the sorted endpoints (identical fp ops in every consumer)
__device__ __forceinline__ void grid_geom(const float2* xe, int n, float* x0, float* hx) {
  float a = xe[0].x - 7.0f;        // ~8 sigma margin in prescaled units
  float b = xe[n - 1].x + 7.0f;
  *x0 = a;
  *hx = (b - a) / (float)(GM - 1);
}

// ---------------------------------------------------------------------------
// Kernel 1: full rank + scatter in ONE dispatch. Block b owns i-keys
// [32b, 32b+32) in registers; each thread streams a 32-element j-stripe and
// compares against all 32 keys. shfl + LDS reduce -> complete ranks -> scatter.
// Side duty: block 16 zeroes out[0] (loss accumulator for K3's atomics).
// ---------------------------------------------------------------------------
__global__ __launch_bounds__(RB) void rank_scatter_kernel(
    const float* __restrict__ theta, const float* __restrict__ dur,
    const int* __restrict__ ev, float2* __restrict__ xe,
    float* __restrict__ th_s, float* __restrict__ out, int n) {
  __shared__ uint64_t kt[IK];
  __shared__ int part[4 * IK];
  const int tid = threadIdx.x, bid = blockIdx.x;
  const int k0 = bid * IK;

  if (tid < IK) kt[tid] = order_key(e_of(theta, dur, k0 + tid), k0 + tid);
  if (bid == 16 && tid == 0) out[0] = 0.0f;
  __syncthreads();

  uint64_t ki[IK];
  int cnt[IK];
  #pragma unroll
  for (int p = 0; p < IK; ++p) { ki[p] = kt[p]; cnt[p] = 0; }

  #pragma unroll 4
  for (int s = 0; s < JS; ++s) {
    int j = s * RB + tid;                            // coalesced stripe
    uint64_t jk = order_key(e_of(theta, dur, j), j);
    #pragma unroll
    for (int p = 0; p < IK; ++p) cnt[p] += (jk < ki[p]) ? 1 : 0;
  }

  // reduce each of the 32 counts across the 64-lane wave, then across waves
  #pragma unroll
  for (int p = 0; p < IK; ++p) {
    #pragma unroll
    for (int off = 32; off > 0; off >>= 1) cnt[p] += __shfl_down(cnt[p], off, 64);
  }
  int wave = tid >> 6, lane = tid & 63;
  if (lane == 0) {
    #pragma unroll
    for (int p = 0; p < IK; ++p) part[wave * IK + p] = cnt[p];
  }
  __syncthreads();

  if (tid < IK) {
    int r = part[tid] + part[IK + tid] + part[2 * IK + tid] + part[3 * IK + tid];
    int k = k0 + tid;
    ((float*)&xe[r])[0] = SCALE * e_of(theta, dur, k);   // scatter (distinct dword)
    ((float*)&xe[k])[1] = (float)ev[r];                  // inverse-perm side reorder
    th_s[k] = theta[r];
  }
}

// ---------------------------------------------------------------------------
// Kernel 2: Gauss transform -> per-group partials, PLAIN coalesced stores.
// No atomics (R5: 524K same-line RMWs serialized), no fence/ticket tail
// (R6: single-CU 512KB post-invalidate reduction = ~30+ us). 256 blocks =
// full machine; block (g, c): sources [g*128,(g+1)*128) staged in LDS, grid
// points m = c*256+tid; stores part[g*4096 + seg*1024 + m], seg = A|B|F|D.
// ---------------------------------------------------------------------------
__global__ __launch_bounds__(RB) void gt_kernel(
    const float2* __restrict__ xe, float* __restrict__ part, int n) {
  __shared__ float2 cst[GCH];
  const int tid = threadIdx.x, bid = blockIdx.x;

  float x0, hx;
  grid_geom(xe, n, &x0, &hx);

  const int c = bid & 3, g = bid >> 2;
  int m = c * RB + tid;
  float xm = fmaf((float)m, hx, x0);
  if (tid < GCH) cst[tid] = xe[g * GCH + tid];   // stage 128 sources
  __syncthreads();
  const float P2S = 0.39169197f;  // 0.47047*sqrt(ln2): t = 1/(1+p|d|/sqrt2)
  float a = 0.0f, b = 0.0f, f = 0.0f, d = 0.0f;
  #pragma unroll 8
  for (int jj = 0; jj < GCH; ++jj) {
    float2 q = cst[jj];                  // LDS broadcast
    float dp = xm - q.x;
    float g2 = __builtin_amdgcn_exp2f(-(dp * dp));  // exp(-d^2/2)
    float evg = q.y * g2;
    a += g2;
    b += evg;
    d = fmaf(dp, evg, d);
    // A&S 7.1.25 erf (p=0.47047, |err|<=2.5e-5), reuses g2
    float tt = __builtin_amdgcn_rcpf(fmaf(P2S, __builtin_fabsf(dp), 1.0f));
    float poly = tt * (0.3480242f + tt * (-0.0958798f + tt * 0.7478556f));
    f += __builtin_copysignf(fmaf(-poly, g2, 1.0f), dp);   // sign*erf
  }
  float* pg = part + g * (4 * GM);
  pg[m]          = a;                    // plain coalesced stores, no contention
  pg[GM + m]     = b;
  pg[2 * GM + m] = 0.5f * (float)GCH + 0.5f * f;   // Phi = .5 + .5*sum(erf)
  pg[3 * GM + m] = d;
}

// ---------------------------------------------------------------------------
// Kernel 3: final. Each of 32 blocks REDUNDANTLY reduces all 64 partials into
// its own LDS gsum (1 MB/block, 32 MB aggregate = L2-resident broadcast; many
// CUs in parallel instead of one CU serially), then Hermite interpolation +
// loss for its contiguous 256-element slice (exactly R0's grouping: one
// element/thread, shfl+LDS reduce, one atomicAdd into zeroed out).
// ---------------------------------------------------------------------------
__global__ __launch_bounds__(RB) void final_kernel(
    const float2* __restrict__ xe, const float* __restrict__ th_s,
    const float* __restrict__ part, float* __restrict__ out, int n) {
  __shared__ float gsum[4 * GM];          // 16 KB
  __shared__ float red[RB / 64];
  const int tid = threadIdx.x, bid = blockIdx.x;

  float x0, hx;
  grid_geom(xe, n, &x0, &hx);

  // ---- broadcast-reduce partials into LDS ----
  {
    const float4* p4 = (const float4*)part;
    float4 a0 = {0, 0, 0, 0}, a1 = {0, 0, 0, 0}, a2 = {0, 0, 0, 0}, a3 = {0, 0, 0, 0};
    #pragma unroll 4
    for (int g = 0; g < G; ++g) {          // deterministic ascending-g order
      const float4* pg = p4 + g * GM;      // 4*GM floats = GM float4s per group
      float4 v0 = pg[tid];
      float4 v1 = pg[256 + tid];
      float4 v2 = pg[512 + tid];
      float4 v3 = pg[768 + tid];
      a0.x += v0.x; a0.y += v0.y; a0.z += v0.z; a0.w += v0.w;
      a1.x += v1.x; a1.y += v1.y; a1.z += v1.z; a1.w += v1.w;
      a2.x += v2.x; a2.y += v2.y; a2.z += v2.z; a2.w += v2.w;
      a3.x += v3.x; a3.y += v3.y; a3.z += v3.z; a3.w += v3.w;
    }
    ((float4*)gsum)[tid]       = a0;
    ((float4*)gsum)[256 + tid] = a1;
    ((float4*)gsum)[512 + tid] = a2;
    ((float4*)gsum)[768 + tid] = a3;
  }
  __syncthreads();

  // ---- Hermite interpolation + loss (gsum in LDS) ----
  const float* A = gsum;
  const float* B = gsum + GM;
  const float* F = gsum + 2 * GM;
  const float* D = gsum + 3 * GM;
  int i = bid * RB + tid;

  float term = 0.0f;
  {
    float2 q = xe[i];
    float u = (q.x - x0) * __builtin_amdgcn_rcpf(hx);
    int m = (int)u;
    m = min(max(m, 0), GM - 2);
    float t = u - (float)m;
    t = fminf(fmaxf(t, 0.0f), 1.0f);
    float t2 = t * t, t3 = t2 * t;
    float h00 = 2.0f * t3 - 3.0f * t2 + 1.0f;
    float h01 = 3.0f * t2 - 2.0f * t3;
    float h10 = t3 - 2.0f * t2 + t;
    float h11 = t3 - t2;
    float Fi = F[m] * h00 + F[m + 1] * h01 +
               hx * KFP * (A[m] * h10 + A[m + 1] * h11);
    float Bi = B[m] * h00 + B[m + 1] * h01 -
               2.0f * LN2 * hx * (D[m] * h10 + D[m + 1] * h11);
    const float fn = (float)n;
    float condE = fmaxf(Bi, 0.0f) * (1.0f / SQRT2PI) / fn + fn * 1e-32f;
    float surv = fmaxf(Fi, 0.25f) / fn;    // exact math gives Fi >= 0.5
    term = (__logf(condE) - __logf(surv) + th_s[i]) * q.y;
  }

  #pragma unroll
  for (int off = 32; off > 0; off >>= 1) term += __shfl_down(term, off, 64);
  int wave = tid >> 6, lane = tid & 63;
  if (lane == 0) red[wave] = term;
  __syncthreads();
  if (tid == 0) {
    float s = 0.0f;
    #pragma unroll
    for (int w = 0; w < RB / 64; ++w) s += red[w];
    atomicAdd(out, -s / (float)n);         // 32 atomics total
  }
}

extern "C" void kernel_launch(void* const* d_in, const int* in_sizes, int n_in,
                              void* d_out, int out_size, void* d_ws, size_t ws_size,
                              hipStream_t stream) {
  const float* theta = (const float*)d_in[0];   // log_h (n,1) fp32
  const float* dur   = (const float*)d_in[1];   // durations (n,) fp32
  const int*   ev    = (const int*)d_in[2];     // events (n,) int32
  float* out = (float*)d_out;
  int n = in_sizes[1];

  // workspace layout (16-byte aligned first for float4 access)
  char* ws = (char*)d_ws;
  float*  part = (float*)ws;   ws += G * 4 * GM * sizeof(float);  // partials
  float2* xe   = (float2*)ws;  ws += n * sizeof(float2);
  float*  th_s = (float*)ws;   ws += n * sizeof(float);

  rank_scatter_kernel<<<KB, RB, 0, stream>>>(theta, dur, ev, xe, th_s, out, n);
  gt_kernel<<<GTB, RB, 0, stream>>>(xe, part, n);
  final_kernel<<<FB, RB, 0, stream>>>(xe, th_s, part, out, n);
}

// Round 8
// 77.562 us; speedup vs baseline: 1.4081x; 1.1579x over previous
//
#include <hip/hip_runtime.h>
#include <math.h>
#include <stdint.h>

#define RB 256      // block size
#define KB 256      // rank blocks (n / IK)
#define IK 32       // i-keys owned per rank block
#define JS 32       // j-iterations per thread in rank phase (n / RB)
#define GM 1024     // Gauss-transform grid points
#define YS 128      // gt source-splits (R2-proven geometry)
#define FB 32       // final blocks (n / RB)

#define SCALE 0.84932180028801904f   // 1/sqrt(2 ln2): exp(-d^2/2) = exp2(-(SCALE*d)^2)
#define SQRT2PI 2.5066282746310002f
#define KFP 0.46971863934f           // 1/(SCALE*sqrt(2pi)) : dPhiSum/dx = KFP*A
#define LN2 0.69314718056f

__device__ __forceinline__ uint64_t order_key(float f, int idx) {
  unsigned u = __float_as_uint(f);
  u = (u & 0x80000000u) ? ~u : (u | 0x80000000u);
  return ((uint64_t)u << 32) | (unsigned)idx;
}

__device__ __forceinline__ float e_of(const float* theta, const float* dur, int i) {
  return logf(dur[i] + 1e-32f) - theta[i];   // deterministic: identical everywhere
}

// grid geometry from the sorted endpoints (identical fp ops in every consumer)
__device__ __forceinline__ void grid_geom(const float2* xe, int n, float* x0, float* hx) {
  float a = xe[0].x - 7.0f;        // ~8 sigma margin in prescaled units
  float b = xe[n - 1].x + 7.0f;
  *x0 = a;
  *hx = (b - a) / (float)(GM - 1);
}

// ---------------------------------------------------------------------------
// Kernel 1: full rank + scatter in ONE dispatch (R7-proven, ~2.5 us). Block b
// owns i-keys [32b, 32b+32) in registers; each thread streams a 32-element
// j-stripe and compares against all 32 keys; shfl + LDS reduce -> complete
// ranks -> immediate scatter. Side duties: blocks 0..15 zero gbuf (4*GM
// floats) for K2's atomics; block 16 zeroes out[0].
// ---------------------------------------------------------------------------
__global__ __launch_bounds__(RB) void rank_scatter_kernel(
    const float* __restrict__ theta, const float* __restrict__ dur,
    const int* __restrict__ ev, float2* __restrict__ xe,
    float* __restrict__ th_s, float* __restrict__ gbuf,
    float* __restrict__ out, int n) {
  __shared__ uint64_t kt[IK];
  __shared__ int part[4 * IK];
  const int tid = threadIdx.x, bid = blockIdx.x;
  const int k0 = bid * IK;

  if (tid < IK) kt[tid] = order_key(e_of(theta, dur, k0 + tid), k0 + tid);
  if (bid < 16) gbuf[bid * RB + tid] = 0.0f;        // 16*256 = 4*GM
  if (bid == 16 && tid == 0) out[0] = 0.0f;
  __syncthreads();

  uint64_t ki[IK];
  int cnt[IK];
  #pragma unroll
  for (int p = 0; p < IK; ++p) { ki[p] = kt[p]; cnt[p] = 0; }

  #pragma unroll 4
  for (int s = 0; s < JS; ++s) {
    int j = s * RB + tid;                            // coalesced stripe
    uint64_t jk = order_key(e_of(theta, dur, j), j);
    #pragma unroll
    for (int p = 0; p < IK; ++p) cnt[p] += (jk < ki[p]) ? 1 : 0;
  }

  // reduce each of the 32 counts across the 64-lane wave, then across waves
  #pragma unroll
  for (int p = 0; p < IK; ++p) {
    #pragma unroll
    for (int off = 32; off > 0; off >>= 1) cnt[p] += __shfl_down(cnt[p], off, 64);
  }
  int wave = tid >> 6, lane = tid & 63;
  if (lane == 0) {
    #pragma unroll
    for (int p = 0; p < IK; ++p) part[wave * IK + p] = cnt[p];
  }
  __syncthreads();

  if (tid < IK) {
    int r = part[tid] + part[IK + tid] + part[2 * IK + tid] + part[3 * IK + tid];
    int k = k0 + tid;
    ((float*)&xe[r])[0] = SCALE * e_of(theta, dur, k);   // scatter (distinct dword)
    ((float*)&xe[k])[1] = (float)ev[r];                  // inverse-perm side reorder
    th_s[k] = theta[r];
  }
}

// ---------------------------------------------------------------------------
// Kernel 2: Gauss transform on the grid (R2-proven verbatim, ~2.5 us incl.
// atomics: 524K RMWs SPREAD over 4096 distinct addresses pipeline fine at the
// coherent point -- unlike same-line chains). dp = x_m - x_j (prescaled).
//   A = sum g; B = sum ev*g; F = sum Phi(d); D = sum dp*ev*g
// ---------------------------------------------------------------------------
__global__ __launch_bounds__(RB) void gt_kernel(
    const float2* __restrict__ xe, float* __restrict__ gbuf, int n) {
  float x0, hx;
  grid_geom(xe, n, &x0, &hx);
  int m = blockIdx.x * RB + threadIdx.x;        // gridDim.x = GM/RB = 4
  float xm = fmaf((float)m, hx, x0);
  const int chunk = n / YS;                      // 64
  int jb = blockIdx.y * chunk;
  const float P2S = 0.39169197f;   // 0.47047*sqrt(ln2): t = 1/(1+p|d|/sqrt2)
  float a = 0.0f, b = 0.0f, f = 0.0f, d = 0.0f;
  #pragma unroll 8
  for (int jj = 0; jj < chunk; ++jj) {
    float2 q = xe[jb + jj];                      // block-uniform address
    float dp = xm - q.x;
    float g = __builtin_amdgcn_exp2f(-(dp * dp));  // exp(-d^2/2)
    float evg = q.y * g;
    a += g;
    b += evg;
    d = fmaf(dp, evg, d);
    // A&S 7.1.25 erf (p=0.47047, |err|<=2.5e-5), reuses g
    float tt = __builtin_amdgcn_rcpf(fmaf(P2S, __builtin_fabsf(dp), 1.0f));
    float poly = tt * (0.3480242f + tt * (-0.0958798f + tt * 0.7478556f));
    f += __builtin_copysignf(fmaf(-poly, g, 1.0f), dp);   // sign*erf
  }
  atomicAdd(&gbuf[m], a);
  atomicAdd(&gbuf[GM + m], b);
  atomicAdd(&gbuf[2 * GM + m], 0.5f * (float)chunk + 0.5f * f);  // Phi = .5+.5*s
  atomicAdd(&gbuf[3 * GM + m], d);
}

// ---------------------------------------------------------------------------
// Kernel 3: per-element cubic Hermite interpolation of FPhi (cdf-sum) and B
// (pdf*ev sum), then the loss terms (R2-proven verbatim, ~1.5 us). gbuf is
// only 16 KB -- served from IF/L2 to all 32 blocks. One atomic per block.
// ---------------------------------------------------------------------------
__global__ __launch_bounds__(RB) void final_kernel(
    const float2* __restrict__ xe, const float* __restrict__ th_s,
    const float* __restrict__ gbuf, float* __restrict__ out, int n) {
  float x0, hx;
  grid_geom(xe, n, &x0, &hx);
  const float* A = gbuf;
  const float* B = gbuf + GM;
  const float* F = gbuf + 2 * GM;
  const float* D = gbuf + 3 * GM;
  int i = blockIdx.x * RB + threadIdx.x;

  float term = 0.0f;
  if (i < n) {
    float2 q = xe[i];
    float u = (q.x - x0) * __builtin_amdgcn_rcpf(hx);
    int m = (int)u;
    m = min(max(m, 0), GM - 2);
    float t = u - (float)m;
    t = fminf(fmaxf(t, 0.0f), 1.0f);
    float t2 = t * t, t3 = t2 * t;
    float h00 = 2.0f * t3 - 3.0f * t2 + 1.0f;
    float h01 = 3.0f * t2 - 2.0f * t3;
    float h10 = t3 - 2.0f * t2 + t;
    float h11 = t3 - t2;
    float Fi = F[m] * h00 + F[m + 1] * h01 +
               hx * KFP * (A[m] * h10 + A[m + 1] * h11);
    float Bi = B[m] * h00 + B[m + 1] * h01 -
               2.0f * LN2 * hx * (D[m] * h10 + D[m + 1] * h11);
    const float fn = (float)n;
    float condE = fmaxf(Bi, 0.0f) * (1.0f / SQRT2PI) / fn + fn * 1e-32f;
    float surv = fmaxf(Fi, 0.25f) / fn;    // exact math gives Fi >= 0.5
    term = (__logf(condE) - __logf(surv) + th_s[i]) * q.y;
  }

  #pragma unroll
  for (int off = 32; off > 0; off >>= 1) term += __shfl_down(term, off, 64);
  __shared__ float red[RB / 64];
  int wave = threadIdx.x >> 6, lane = threadIdx.x & 63;
  if (lane == 0) red[wave] = term;
  __syncthreads();
  if (threadIdx.x == 0) {
    float s = 0.0f;
    #pragma unroll
    for (int w = 0; w < RB / 64; ++w) s += red[w];
    atomicAdd(out, -s / (float)n);
  }
}

extern "C" void kernel_launch(void* const* d_in, const int* in_sizes, int n_in,
                              void* d_out, int out_size, void* d_ws, size_t ws_size,
                              hipStream_t stream) {
  const float* theta = (const float*)d_in[0];   // log_h (n,1) fp32
  const float* dur   = (const float*)d_in[1];   // durations (n,) fp32
  const int*   ev    = (const int*)d_in[2];     // events (n,) int32
  float* out = (float*)d_out;
  int n = in_sizes[1];

  // workspace layout (8-byte aligned first)
  char* ws = (char*)d_ws;
  float2* xe   = (float2*)ws;  ws += n * sizeof(float2);
  float*  th_s = (float*)ws;   ws += n * sizeof(float);
  float*  gbuf = (float*)ws;   ws += 4 * GM * sizeof(float);  // A|B|F|D

  rank_scatter_kernel<<<KB, RB, 0, stream>>>(theta, dur, ev, xe, th_s,
                                             gbuf, out, n);
  gt_kernel<<<dim3(GM / RB, YS), RB, 0, stream>>>(xe, gbuf, n);
  final_kernel<<<FB, RB, 0, stream>>>(xe, th_s, gbuf, out, n);
}